// Round 2
// 204.131 us; speedup vs baseline: 1.0432x; 1.0432x over previous
//
#include <hip/hip_runtime.h>
#include <stdint.h>

typedef unsigned short u16;
typedef __bf16 bf16x8 __attribute__((ext_vector_type(8)));
typedef float f32x4 __attribute__((ext_vector_type(4)));
typedef float f32x2 __attribute__((ext_vector_type(2)));

#define M_ROWS 16384
#define K_DIM  1568
#define H_DIM  128
#define NQ     384
#define MT     32              // batch rows per block
#define BK     32
#define NSTEP  49              // K_DIM / BK
#define CH_F   384             // floats per row per chunk (12 ksteps)
#define ASTR   392             // chunk LDS row stride in u16 (384 + 8 pad)
#define TSTR   40              // tail LDS row stride in u16 (32 + 8 pad)
#define ABUF   (MT * ASTR)     // 12544 u16 per chunk buffer
#define PSTR   132             // P row stride in f32
#define KSTRIDE (NQ * BK)      // wt2 elements per kstep = 12288
#define SCALE  0.02525381361380526f   // 1/sqrt(1568)
#define LOG2E  1.4426950408889634f

__device__ __forceinline__ u16 f32_to_bf16_rne(float f) {
    uint32_t u = __float_as_uint(f);
    uint32_t r = (u + 0x7FFFu + ((u >> 16) & 1u)) >> 16;
    return (u16)r;
}

__device__ __forceinline__ uint32_t cvt_pk(float lo, float hi) {
    uint32_t d;
    asm("v_cvt_pk_bf16_f32 %0, %1, %2" : "=v"(d) : "v"(lo), "v"(hi));
    return d;
}

__device__ __forceinline__ f32x2 pk_mul(f32x2 a, f32x2 b) {
    f32x2 d; asm("v_pk_mul_f32 %0, %1, %2" : "=v"(d) : "v"(a), "v"(b)); return d;
}
__device__ __forceinline__ f32x2 pk_add(f32x2 a, f32x2 b) {
    f32x2 d; asm("v_pk_add_f32 %0, %1, %2" : "=v"(d) : "v"(a), "v"(b)); return d;
}
__device__ __forceinline__ f32x2 pk_fma(f32x2 a, f32x2 b, f32x2 c) {
    f32x2 d; asm("v_pk_fma_f32 %0, %1, %2, %3" : "=v"(d) : "v"(a), "v"(b), "v"(c)); return d;
}

__device__ __forceinline__ void cvt_wr8(u16* dst, f32x4 v) {
    uint2 t; t.x = cvt_pk(v.x, v.y); t.y = cvt_pk(v.z, v.w);
    *(uint2*)dst = t;
}

#define MFMA(a, b, c) __builtin_amdgcn_mfma_f32_16x16x32_bf16(a, b, c, 0, 0, 0)

// ---------------------------------------------------------------------------
// Kernel 1: weights -> fragment-ordered wt2[(kstep*384 + n)*32 + klo] (bf16)
// ---------------------------------------------------------------------------
__global__ __launch_bounds__(256) void wtrans_kernel(
    const float* __restrict__ wq, const float* __restrict__ wk,
    const float* __restrict__ wv, u16* __restrict__ wt2)
{
    __shared__ u16 tile[32][33];
    const float* w = (blockIdx.z == 0) ? wq : (blockIdx.z == 1) ? wk : wv;
    const int k0 = blockIdx.x * 32;
    const int nloc0 = blockIdx.y * 32;
    const int ng0 = blockIdx.z * 128 + nloc0;

    const int tn = threadIdx.x & 31;
    const int tk = threadIdx.x >> 5;
    #pragma unroll
    for (int p = 0; p < 4; p++) {
        int kk = tk + p * 8;
        tile[kk][tn] = f32_to_bf16_rne(w[(size_t)(k0 + kk) * H_DIM + nloc0 + tn]);
    }
    __syncthreads();

    const int klo = threadIdx.x & 31;
    const int tn2 = threadIdx.x >> 5;
    u16* dst = wt2 + (size_t)(k0 >> 5) * KSTRIDE;
    #pragma unroll
    for (int p = 0; p < 4; p++) {
        int nn = tn2 + p * 8;
        dst[(size_t)(ng0 + nn) * 32 + klo] = tile[klo][nn];
    }
}

// ---------------------------------------------------------------------------
// Kernel 2 (fused): 512 threads = 8 waves, 32 batch rows per block.
// 4-chunk double-buffered async A staging: loads for chunk c+2 in flight
// (held in regs) while chunk c computes; cvt_pk conversion; one barrier/chunk.
// Attention: rank-1 softmax with packed-f32 (pk_mul/pk_add/pk_fma) inner loop.
// ---------------------------------------------------------------------------
__global__ __launch_bounds__(512, 4) void fused_kernel(
    const float* __restrict__ x,     // [M,K] fp32
    const u16* __restrict__ wt2,     // fragment-ordered weights
    float* __restrict__ out)         // [M,H] fp32
{
    __shared__ char smem[2 * ABUF * 2 + MT * TSTR * 2];   // 50176 + 2560 = 52736 B
    u16* A0 = (u16*)smem;
    u16* A1 = A0 + ABUF;
    u16* TB = A1 + ABUF;
    float (*Pq)[PSTR] = (float (*)[PSTR])smem;
    float (*Pk)[PSTR] = (float (*)[PSTR])(smem + MT * PSTR * 4);
    float (*Pv)[PSTR] = (float (*)[PSTR])(smem + 2 * MT * PSTR * 4);

    const int tid  = threadIdx.x;
    const int lane = tid & 63;
    const int wave = tid >> 6;
    const int lrow = lane & 15;
    const int quad = lane >> 4;
    const int m0   = blockIdx.x * MT;

    // ---- B fragment pointers: contiguous 16B/lane in wt2 ----
    const u16* bp0 = wt2 + (size_t)(wave * 48 +  0 + lrow) * 32 + quad * 8;
    const u16* bp1 = wt2 + (size_t)(wave * 48 + 16 + lrow) * 32 + quad * 8;
    const u16* bp2 = wt2 + (size_t)(wave * 48 + 32 + lrow) * 32 + quad * 8;

    // ---- staging geometry: 16 threads per row, f32x4 granules, NT loads ----
    const int srow = tid >> 4;
    const int st16 = tid & 15;
    const float* xrow = x + (size_t)(m0 + srow) * K_DIM;
    u16* wb0 = A0 + srow * ASTR + st16 * 4;
    u16* wb1 = A1 + srow * ASTR + st16 * 4;

    const u16* aA0 = A0 + lrow * ASTR + quad * 8;
    const u16* aA1 = A0 + (16 + lrow) * ASTR + quad * 8;
    const u16* aB0 = A1 + lrow * ASTR + quad * 8;
    const u16* aB1 = A1 + (16 + lrow) * ASTR + quad * 8;

#define NTLD4(off) __builtin_nontemporal_load((const f32x4*)(xrow + (off)))
#define LOADC(S, OFF) do { \
    S##0 = NTLD4((OFF) + st16 * 4 +   0); \
    S##1 = NTLD4((OFF) + st16 * 4 +  64); \
    S##2 = NTLD4((OFF) + st16 * 4 + 128); \
    S##3 = NTLD4((OFF) + st16 * 4 + 192); \
    S##4 = NTLD4((OFF) + st16 * 4 + 256); \
    S##5 = NTLD4((OFF) + st16 * 4 + 320); \
} while (0)
#define WRITEC(WB, S) do { \
    cvt_wr8((WB) +   0, S##0); cvt_wr8((WB) +  64, S##1); \
    cvt_wr8((WB) + 128, S##2); cvt_wr8((WB) + 192, S##3); \
    cvt_wr8((WB) + 256, S##4); cvt_wr8((WB) + 320, S##5); \
} while (0)

    f32x4 acc00 = {}, acc01 = {}, acc02 = {};
    f32x4 acc10 = {}, acc11 = {}, acc12 = {};
    f32x4 s00, s01, s02, s03, s04, s05;
    f32x4 s10, s11, s12, s13, s14, s15;

    // ================= prologue: chunk0 + tail staged, chunk1 in flight =====
    LOADC(s0, 0);
    f32x2 tl = __builtin_nontemporal_load((const f32x2*)(xrow + 1536 + st16 * 2));
    LOADC(s1, CH_F);
    WRITEC(wb0, s0);
    *(uint32_t*)(TB + srow * TSTR + st16 * 2) = cvt_pk(tl.x, tl.y);

    // ---- B depth-2 register pipeline prologue ----
    bf16x8 Ba0 = *(const bf16x8*)(bp0);
    bf16x8 Ba1 = *(const bf16x8*)(bp1);
    bf16x8 Ba2 = *(const bf16x8*)(bp2);
    bf16x8 Bb0 = *(const bf16x8*)(bp0 + KSTRIDE);
    bf16x8 Bb1 = *(const bf16x8*)(bp1 + KSTRIDE);
    bf16x8 Bb2 = *(const bf16x8*)(bp2 + KSTRIDE);
    __syncthreads();

#define KSTEP(P0, P1, IT, G) do { \
    int gp = (G) + 2; if (gp > NSTEP - 1) gp = NSTEP - 1; \
    const size_t o = (size_t)gp * KSTRIDE; \
    bf16x8 Bc0 = *(const bf16x8*)(bp0 + o); \
    bf16x8 Bc1 = *(const bf16x8*)(bp1 + o); \
    bf16x8 Bc2 = *(const bf16x8*)(bp2 + o); \
    bf16x8 a0 = *(const bf16x8*)((P0) + (IT) * BK); \
    bf16x8 a1 = *(const bf16x8*)((P1) + (IT) * BK); \
    acc00 = MFMA(a0, Ba0, acc00); acc10 = MFMA(a1, Ba0, acc10); \
    acc01 = MFMA(a0, Ba1, acc01); acc11 = MFMA(a1, Ba1, acc11); \
    acc02 = MFMA(a0, Ba2, acc02); acc12 = MFMA(a1, Ba2, acc12); \
    Ba0 = Bb0; Ba1 = Bb1; Ba2 = Bb2; Bb0 = Bc0; Bb1 = Bc1; Bb2 = Bc2; \
} while (0)

    // ===== chunk 0: write chunk1, issue chunk2, compute ksteps 0..11 ========
    WRITEC(wb1, s1);
    LOADC(s0, 2 * CH_F);
    #pragma unroll
    for (int it = 0; it < 12; ++it) KSTEP(aA0, aA1, it, it);
    __syncthreads();

    // ===== chunk 1: write chunk2, issue chunk3, compute ksteps 12..23 =======
    WRITEC(wb0, s0);
    LOADC(s1, 3 * CH_F);
    #pragma unroll
    for (int it = 0; it < 12; ++it) KSTEP(aB0, aB1, it, 12 + it);
    __syncthreads();

    // ===== chunk 2: write chunk3, compute ksteps 24..35 =====================
    WRITEC(wb1, s1);
    #pragma unroll
    for (int it = 0; it < 12; ++it) KSTEP(aA0, aA1, it, 24 + it);
    __syncthreads();

    // ===== chunk 3: compute ksteps 36..47 ===================================
    #pragma unroll
    for (int it = 0; it < 12; ++it) KSTEP(aB0, aB1, it, 36 + it);

    // ===== tail kstep 48 from TB (Ba holds g=48 fragments) ==================
    {
        bf16x8 a0 = *(const bf16x8*)(TB + lrow * TSTR + quad * 8);
        bf16x8 a1 = *(const bf16x8*)(TB + (16 + lrow) * TSTR + quad * 8);
        acc00 = MFMA(a0, Ba0, acc00); acc10 = MFMA(a1, Ba0, acc10);
        acc01 = MFMA(a0, Ba1, acc01); acc11 = MFMA(a1, Ba1, acc11);
        acc02 = MFMA(a0, Ba2, acc02); acc12 = MFMA(a1, Ba2, acc12);
    }
    __syncthreads();   // all A/TB reads done before P overwrites the buffers

    // ---- scatter projections to LDS (D: row = quad*4+r, col = lane&15) ----
#define SCAT(ACC, MTi, NTi) do { \
    const int base = wave * 48 + (NTi) * 16; \
    const int sel  = base >> 7; \
    const int col  = (base & 127) + lrow; \
    const int mrow = (MTi) * 16 + quad * 4; \
    if (sel == 0)      { _Pragma("unroll") for (int rr = 0; rr < 4; rr++) Pq[mrow + rr][col] = ACC[rr] * (SCALE * LOG2E); } \
    else if (sel == 1) { _Pragma("unroll") for (int rr = 0; rr < 4; rr++) Pk[mrow + rr][col] = ACC[rr]; } \
    else               { _Pragma("unroll") for (int rr = 0; rr < 4; rr++) Pv[mrow + rr][col] = ACC[rr]; } \
} while (0)

    SCAT(acc00, 0, 0); SCAT(acc01, 0, 1); SCAT(acc02, 0, 2);
    SCAT(acc10, 1, 0); SCAT(acc11, 1, 1); SCAT(acc12, 1, 2);
    __syncthreads();

    // ---- attention: r = row (32), sub (16) x 8 outputs each, packed f32 ----
    const int r   = tid >> 4;
    const int sub = tid & 15;

    f32x4 qa = *(const f32x4*)&Pq[r][sub * 8];
    f32x4 qb = *(const f32x4*)&Pq[r][sub * 8 + 4];
    f32x2 q01; q01.x = qa.x; q01.y = qa.y;
    f32x2 q23; q23.x = qa.z; q23.y = qa.w;
    f32x2 q45; q45.x = qb.x; q45.y = qb.y;
    f32x2 q67; q67.x = qb.z; q67.y = qb.w;

    f32x2 d01 = {}, d23 = {}, d45 = {}, d67 = {};
    f32x2 n01 = {}, n23 = {}, n45 = {}, n67 = {};

    #pragma unroll 2
    for (int j4 = 0; j4 < 32; ++j4) {
        f32x4 k4 = *(const f32x4*)&Pk[r][j4 * 4];
        f32x4 v4 = *(const f32x4*)&Pv[r][j4 * 4];
        #pragma unroll
        for (int jj = 0; jj < 4; ++jj) {
            float kj = k4[jj];
            float vj = v4[jj];
            f32x2 kk; kk.x = kj; kk.y = kj;
            f32x2 vv; vv.x = vj; vv.y = vj;
            f32x2 sc01 = pk_mul(q01, kk);
            f32x2 sc23 = pk_mul(q23, kk);
            f32x2 sc45 = pk_mul(q45, kk);
            f32x2 sc67 = pk_mul(q67, kk);
            f32x2 e01; e01.x = __builtin_amdgcn_exp2f(sc01.x); e01.y = __builtin_amdgcn_exp2f(sc01.y);
            f32x2 e23; e23.x = __builtin_amdgcn_exp2f(sc23.x); e23.y = __builtin_amdgcn_exp2f(sc23.y);
            f32x2 e45; e45.x = __builtin_amdgcn_exp2f(sc45.x); e45.y = __builtin_amdgcn_exp2f(sc45.y);
            f32x2 e67; e67.x = __builtin_amdgcn_exp2f(sc67.x); e67.y = __builtin_amdgcn_exp2f(sc67.y);
            d01 = pk_add(d01, e01); n01 = pk_fma(e01, vv, n01);
            d23 = pk_add(d23, e23); n23 = pk_fma(e23, vv, n23);
            d45 = pk_add(d45, e45); n45 = pk_fma(e45, vv, n45);
            d67 = pk_add(d67, e67); n67 = pk_fma(e67, vv, n67);
        }
    }

    float* op = out + (size_t)(m0 + r) * H_DIM + sub * 8;
    f32x4 o0, o1;
    o0.x = n01.x / d01.x; o0.y = n01.y / d01.y;
    o0.z = n23.x / d23.x; o0.w = n23.y / d23.y;
    o1.x = n45.x / d45.x; o1.y = n45.y / d45.y;
    o1.z = n67.x / d67.x; o1.w = n67.y / d67.y;
    __builtin_nontemporal_store(o0, (f32x4*)(op));
    __builtin_nontemporal_store(o1, (f32x4*)(op + 4));
}

// ---------------------------------------------------------------------------
extern "C" void kernel_launch(void* const* d_in, const int* in_sizes, int n_in,
                              void* d_out, int out_size, void* d_ws, size_t ws_size,
                              hipStream_t stream)
{
    const float* x  = (const float*)d_in[0];
    const float* wq = (const float*)d_in[1];
    const float* wk = (const float*)d_in[2];
    const float* wv = (const float*)d_in[3];
    float* out = (float*)d_out;

    u16* wt2 = (u16*)d_ws;   // 49*384*32 u16 = 1.2 MB

    wtrans_kernel<<<dim3(K_DIM / 32, H_DIM / 32, 3), 256, 0, stream>>>(wq, wk, wv, wt2);
    fused_kernel<<<M_ROWS / MT, 512, 0, stream>>>(x, wt2, out);
}

// Round 3
// 195.851 us; speedup vs baseline: 1.0873x; 1.0423x over previous
//
#include <hip/hip_runtime.h>
#include <stdint.h>

typedef unsigned short u16;
typedef __bf16 bf16x8 __attribute__((ext_vector_type(8)));
typedef float f32x4 __attribute__((ext_vector_type(4)));
typedef float f32x2 __attribute__((ext_vector_type(2)));

#define M_ROWS 16384
#define K_DIM  1568
#define H_DIM  128
#define NQ     384
#define MT     64              // batch rows per block (1 block/CU)
#define BK     32
#define NSTEP  49              // K_DIM / BK
#define NCH    8               // full chunks of 6 ksteps
#define CH_F   192             // floats per row per chunk (6 ksteps)
#define ASTR   200             // chunk LDS row stride in u16 (192 + 8 pad -> granule-balanced)
#define TSTR   40              // tail LDS row stride in u16
#define ABUF   (MT * ASTR)     // 12800 u16 per chunk buffer
#define PSTR   132             // P row stride in f32
#define KSTRIDE (NQ * BK)      // wt2 elements per kstep = 12288
#define SCALE  0.02525381361380526f   // 1/sqrt(1568)
#define LOG2E  1.4426950408889634f

__device__ __forceinline__ u16 f32_to_bf16_rne(float f) {
    uint32_t u = __float_as_uint(f);
    uint32_t r = (u + 0x7FFFu + ((u >> 16) & 1u)) >> 16;
    return (u16)r;
}

__device__ __forceinline__ uint32_t cvt_pk(float lo, float hi) {
    uint32_t d;
    asm("v_cvt_pk_bf16_f32 %0, %1, %2" : "=v"(d) : "v"(lo), "v"(hi));
    return d;
}

__device__ __forceinline__ f32x2 pk_mul(f32x2 a, f32x2 b) {
    f32x2 d; asm("v_pk_mul_f32 %0, %1, %2" : "=v"(d) : "v"(a), "v"(b)); return d;
}
__device__ __forceinline__ f32x2 pk_add(f32x2 a, f32x2 b) {
    f32x2 d; asm("v_pk_add_f32 %0, %1, %2" : "=v"(d) : "v"(a), "v"(b)); return d;
}
__device__ __forceinline__ f32x2 pk_fma(f32x2 a, f32x2 b, f32x2 c) {
    f32x2 d; asm("v_pk_fma_f32 %0, %1, %2, %3" : "=v"(d) : "v"(a), "v"(b), "v"(c)); return d;
}

__device__ __forceinline__ void cvt_wr8(u16* dst, f32x4 v) {
    uint2 t; t.x = cvt_pk(v.x, v.y); t.y = cvt_pk(v.z, v.w);
    *(uint2*)dst = t;
}

#define MFMA(a, b, c) __builtin_amdgcn_mfma_f32_16x16x32_bf16(a, b, c, 0, 0, 0)

// ---------------------------------------------------------------------------
// Kernel 1: weights -> fragment-ordered wt2[(kstep*384 + n)*32 + klo] (bf16)
// ---------------------------------------------------------------------------
__global__ __launch_bounds__(256) void wtrans_kernel(
    const float* __restrict__ wq, const float* __restrict__ wk,
    const float* __restrict__ wv, u16* __restrict__ wt2)
{
    __shared__ u16 tile[32][33];
    const float* w = (blockIdx.z == 0) ? wq : (blockIdx.z == 1) ? wk : wv;
    const int k0 = blockIdx.x * 32;
    const int nloc0 = blockIdx.y * 32;
    const int ng0 = blockIdx.z * 128 + nloc0;

    const int tn = threadIdx.x & 31;
    const int tk = threadIdx.x >> 5;
    #pragma unroll
    for (int p = 0; p < 4; p++) {
        int kk = tk + p * 8;
        tile[kk][tn] = f32_to_bf16_rne(w[(size_t)(k0 + kk) * H_DIM + nloc0 + tn]);
    }
    __syncthreads();

    const int klo = threadIdx.x & 31;
    const int tn2 = threadIdx.x >> 5;
    u16* dst = wt2 + (size_t)(k0 >> 5) * KSTRIDE;
    #pragma unroll
    for (int p = 0; p < 4; p++) {
        int nn = tn2 + p * 8;
        dst[(size_t)(ng0 + nn) * 32 + klo] = tile[klo][nn];
    }
}

// ---------------------------------------------------------------------------
// Kernel 2 (fused): 512 threads = 8 waves, 64 batch rows per block, grid 256
// (1 block/CU). GEMM: 8 chunks x 6 ksteps + tail, double-buffered bf16 LDS,
// staged loads double-buffered in regs (chunk c+2 in flight while c computes);
// depth-2 B register pipeline from fragment-ordered wt2 (1.2MB/block from L2).
// Attention: rank-1 softmax, 8 threads/row x 16 outputs, packed-f32 VALU.
// ---------------------------------------------------------------------------
__global__ __launch_bounds__(512, 2) void fused_kernel(
    const float* __restrict__ x,     // [M,K] fp32
    const u16* __restrict__ wt2,     // fragment-ordered weights
    float* __restrict__ out)         // [M,H] fp32
{
    __shared__ char smem[3 * MT * PSTR * 4];   // 101376 B (P view is the peak)
    u16* A0 = (u16*)smem;
    u16* A1 = A0 + ABUF;
    u16* TB = A1 + ABUF;                        // bytes [51200, 56320)
    float (*Pq)[PSTR] = (float (*)[PSTR])smem;
    float (*Pk)[PSTR] = (float (*)[PSTR])(smem + MT * PSTR * 4);
    float (*Pv)[PSTR] = (float (*)[PSTR])(smem + 2 * MT * PSTR * 4);

    const int tid  = threadIdx.x;
    const int lane = tid & 63;
    const int wave = tid >> 6;
    const int lrow = lane & 15;
    const int quad = lane >> 4;
    const int m0   = blockIdx.x * MT;

    // ---- B fragment pointers: contiguous 16B/lane in wt2 ----
    const u16* bp0 = wt2 + (size_t)(wave * 48 +  0 + lrow) * 32 + quad * 8;
    const u16* bp1 = wt2 + (size_t)(wave * 48 + 16 + lrow) * 32 + quad * 8;
    const u16* bp2 = wt2 + (size_t)(wave * 48 + 32 + lrow) * 32 + quad * 8;

    // ---- staging geometry: 8 threads per row, f32x4 granules, NT loads ----
    const int srow = tid >> 3;           // 0..63
    const int st8  = tid & 7;
    const float* xrow = x + (size_t)(m0 + srow) * K_DIM;
    u16* wbs[2];
    wbs[0] = A0 + srow * ASTR + st8 * 4;
    wbs[1] = A1 + srow * ASTR + st8 * 4;

    // ---- A fragment read pointers (4 m-frags per buffer) ----
    const u16* aF[2][4];
    #pragma unroll
    for (int m = 0; m < 4; m++) {
        aF[0][m] = A0 + (m * 16 + lrow) * ASTR + quad * 8;
        aF[1][m] = A1 + (m * 16 + lrow) * ASTR + quad * 8;
    }

#define NTLD4(off) __builtin_nontemporal_load((const f32x4*)(xrow + (off)))
#define LOADC(S, OFF) do { \
    S[0] = NTLD4((OFF) + st8 * 4 +   0); \
    S[1] = NTLD4((OFF) + st8 * 4 +  32); \
    S[2] = NTLD4((OFF) + st8 * 4 +  64); \
    S[3] = NTLD4((OFF) + st8 * 4 +  96); \
    S[4] = NTLD4((OFF) + st8 * 4 + 128); \
    S[5] = NTLD4((OFF) + st8 * 4 + 160); \
} while (0)
#define WRITEC(WB, S) do { \
    cvt_wr8((WB) +   0, S[0]); cvt_wr8((WB) +  32, S[1]); \
    cvt_wr8((WB) +  64, S[2]); cvt_wr8((WB) +  96, S[3]); \
    cvt_wr8((WB) + 128, S[4]); cvt_wr8((WB) + 160, S[5]); \
} while (0)

    f32x4 acc00 = {}, acc01 = {}, acc02 = {};
    f32x4 acc10 = {}, acc11 = {}, acc12 = {};
    f32x4 acc20 = {}, acc21 = {}, acc22 = {};
    f32x4 acc30 = {}, acc31 = {}, acc32 = {};
    f32x4 sreg[2][6];

    // ================= prologue: chunk0 staged, chunk1 in flight, tail =====
    LOADC(sreg[0], 0);
    f32x4 tl = NTLD4(1536 + st8 * 4);
    LOADC(sreg[1], CH_F);
    WRITEC(wbs[0], sreg[0]);
    cvt_wr8(TB + srow * TSTR + st8 * 4, tl);

    // ---- B depth-2 register pipeline prologue ----
    bf16x8 Ba0 = *(const bf16x8*)(bp0);
    bf16x8 Ba1 = *(const bf16x8*)(bp1);
    bf16x8 Ba2 = *(const bf16x8*)(bp2);
    bf16x8 Bb0 = *(const bf16x8*)(bp0 + KSTRIDE);
    bf16x8 Bb1 = *(const bf16x8*)(bp1 + KSTRIDE);
    bf16x8 Bb2 = *(const bf16x8*)(bp2 + KSTRIDE);
    __syncthreads();

#define KSTEP(AP, IT, G) do { \
    int gp = (G) + 2; if (gp > NSTEP - 1) gp = NSTEP - 1; \
    const size_t o = (size_t)gp * KSTRIDE; \
    bf16x8 Bc0 = *(const bf16x8*)(bp0 + o); \
    bf16x8 Bc1 = *(const bf16x8*)(bp1 + o); \
    bf16x8 Bc2 = *(const bf16x8*)(bp2 + o); \
    bf16x8 a0 = *(const bf16x8*)((AP)[0] + (IT) * BK); \
    bf16x8 a1 = *(const bf16x8*)((AP)[1] + (IT) * BK); \
    bf16x8 a2 = *(const bf16x8*)((AP)[2] + (IT) * BK); \
    bf16x8 a3 = *(const bf16x8*)((AP)[3] + (IT) * BK); \
    acc00 = MFMA(a0, Ba0, acc00); acc10 = MFMA(a1, Ba0, acc10); \
    acc20 = MFMA(a2, Ba0, acc20); acc30 = MFMA(a3, Ba0, acc30); \
    acc01 = MFMA(a0, Ba1, acc01); acc11 = MFMA(a1, Ba1, acc11); \
    acc21 = MFMA(a2, Ba1, acc21); acc31 = MFMA(a3, Ba1, acc31); \
    acc02 = MFMA(a0, Ba2, acc02); acc12 = MFMA(a1, Ba2, acc12); \
    acc22 = MFMA(a2, Ba2, acc22); acc32 = MFMA(a3, Ba2, acc32); \
    Ba0 = Bb0; Ba1 = Bb1; Ba2 = Bb2; Bb0 = Bc0; Bb1 = Bc1; Bb2 = Bc2; \
} while (0)

    // ===== 8 chunks: write c+1, issue c+2, compute c (fully unrolled) ======
    #pragma unroll
    for (int c = 0; c < NCH; ++c) {
        if (c < NCH - 1) WRITEC(wbs[(c + 1) & 1], sreg[(c + 1) & 1]);
        if (c < NCH - 2) LOADC(sreg[c & 1], (c + 2) * CH_F);
        #pragma unroll
        for (int it = 0; it < 6; ++it) KSTEP(aF[c & 1], it, c * 6 + it);
        __syncthreads();
    }

    // ===== tail kstep 48 from TB (Ba holds g=48 fragments) ==================
    {
        bf16x8 a0 = *(const bf16x8*)(TB + (lrow +  0) * TSTR + quad * 8);
        bf16x8 a1 = *(const bf16x8*)(TB + (lrow + 16) * TSTR + quad * 8);
        bf16x8 a2 = *(const bf16x8*)(TB + (lrow + 32) * TSTR + quad * 8);
        bf16x8 a3 = *(const bf16x8*)(TB + (lrow + 48) * TSTR + quad * 8);
        acc00 = MFMA(a0, Ba0, acc00); acc10 = MFMA(a1, Ba0, acc10);
        acc20 = MFMA(a2, Ba0, acc20); acc30 = MFMA(a3, Ba0, acc30);
        acc01 = MFMA(a0, Ba1, acc01); acc11 = MFMA(a1, Ba1, acc11);
        acc21 = MFMA(a2, Ba1, acc21); acc31 = MFMA(a3, Ba1, acc31);
        acc02 = MFMA(a0, Ba2, acc02); acc12 = MFMA(a1, Ba2, acc12);
        acc22 = MFMA(a2, Ba2, acc22); acc32 = MFMA(a3, Ba2, acc32);
    }
    __syncthreads();   // all A/TB reads done before P overwrites the buffers

    // ---- scatter projections to LDS (D: row = quad*4+rr, col = lane&15) ---
#define SCAT(ACC, MTi, NTi) do { \
    const int base = wave * 48 + (NTi) * 16; \
    const int sel  = base >> 7; \
    const int col  = (base & 127) + lrow; \
    const int mrow = (MTi) * 16 + quad * 4; \
    if (sel == 0)      { _Pragma("unroll") for (int rr = 0; rr < 4; rr++) Pq[mrow + rr][col] = ACC[rr] * (SCALE * LOG2E); } \
    else if (sel == 1) { _Pragma("unroll") for (int rr = 0; rr < 4; rr++) Pk[mrow + rr][col] = ACC[rr]; } \
    else               { _Pragma("unroll") for (int rr = 0; rr < 4; rr++) Pv[mrow + rr][col] = ACC[rr]; } \
} while (0)

    SCAT(acc00, 0, 0); SCAT(acc01, 0, 1); SCAT(acc02, 0, 2);
    SCAT(acc10, 1, 0); SCAT(acc11, 1, 1); SCAT(acc12, 1, 2);
    SCAT(acc20, 2, 0); SCAT(acc21, 2, 1); SCAT(acc22, 2, 2);
    SCAT(acc30, 3, 0); SCAT(acc31, 3, 1); SCAT(acc32, 3, 2);
    __syncthreads();

    // ---- attention: r = row (64), sub (8) x 16 outputs each, packed f32 ---
    const int r   = tid >> 3;
    const int sub = tid & 7;

    f32x4 qa = *(const f32x4*)&Pq[r][sub * 16 +  0];
    f32x4 qb = *(const f32x4*)&Pq[r][sub * 16 +  4];
    f32x4 qc = *(const f32x4*)&Pq[r][sub * 16 +  8];
    f32x4 qd = *(const f32x4*)&Pq[r][sub * 16 + 12];
    f32x2 qp0; qp0.x = qa.x; qp0.y = qa.y;
    f32x2 qp1; qp1.x = qa.z; qp1.y = qa.w;
    f32x2 qp2; qp2.x = qb.x; qp2.y = qb.y;
    f32x2 qp3; qp3.x = qb.z; qp3.y = qb.w;
    f32x2 qp4; qp4.x = qc.x; qp4.y = qc.y;
    f32x2 qp5; qp5.x = qc.z; qp5.y = qc.w;
    f32x2 qp6; qp6.x = qd.x; qp6.y = qd.y;
    f32x2 qp7; qp7.x = qd.z; qp7.y = qd.w;

    f32x2 d0 = {}, d1 = {}, d2 = {}, d3 = {}, d4 = {}, d5 = {}, d6 = {}, d7 = {};
    f32x2 n0 = {}, n1 = {}, n2 = {}, n3 = {}, n4 = {}, n5 = {}, n6 = {}, n7 = {};

    #pragma unroll 2
    for (int j4 = 0; j4 < 32; ++j4) {
        f32x4 k4 = *(const f32x4*)&Pk[r][j4 * 4];
        f32x4 v4 = *(const f32x4*)&Pv[r][j4 * 4];
        #pragma unroll
        for (int jj = 0; jj < 4; ++jj) {
            float kj = k4[jj];
            float vj = v4[jj];
            f32x2 kk; kk.x = kj; kk.y = kj;
            f32x2 vv; vv.x = vj; vv.y = vj;
            f32x2 s0 = pk_mul(qp0, kk);
            f32x2 s1 = pk_mul(qp1, kk);
            f32x2 s2 = pk_mul(qp2, kk);
            f32x2 s3 = pk_mul(qp3, kk);
            f32x2 s4 = pk_mul(qp4, kk);
            f32x2 s5 = pk_mul(qp5, kk);
            f32x2 s6 = pk_mul(qp6, kk);
            f32x2 s7 = pk_mul(qp7, kk);
            f32x2 e0; e0.x = __builtin_amdgcn_exp2f(s0.x); e0.y = __builtin_amdgcn_exp2f(s0.y);
            f32x2 e1; e1.x = __builtin_amdgcn_exp2f(s1.x); e1.y = __builtin_amdgcn_exp2f(s1.y);
            f32x2 e2; e2.x = __builtin_amdgcn_exp2f(s2.x); e2.y = __builtin_amdgcn_exp2f(s2.y);
            f32x2 e3; e3.x = __builtin_amdgcn_exp2f(s3.x); e3.y = __builtin_amdgcn_exp2f(s3.y);
            f32x2 e4; e4.x = __builtin_amdgcn_exp2f(s4.x); e4.y = __builtin_amdgcn_exp2f(s4.y);
            f32x2 e5; e5.x = __builtin_amdgcn_exp2f(s5.x); e5.y = __builtin_amdgcn_exp2f(s5.y);
            f32x2 e6; e6.x = __builtin_amdgcn_exp2f(s6.x); e6.y = __builtin_amdgcn_exp2f(s6.y);
            f32x2 e7; e7.x = __builtin_amdgcn_exp2f(s7.x); e7.y = __builtin_amdgcn_exp2f(s7.y);
            d0 = pk_add(d0, e0); n0 = pk_fma(e0, vv, n0);
            d1 = pk_add(d1, e1); n1 = pk_fma(e1, vv, n1);
            d2 = pk_add(d2, e2); n2 = pk_fma(e2, vv, n2);
            d3 = pk_add(d3, e3); n3 = pk_fma(e3, vv, n3);
            d4 = pk_add(d4, e4); n4 = pk_fma(e4, vv, n4);
            d5 = pk_add(d5, e5); n5 = pk_fma(e5, vv, n5);
            d6 = pk_add(d6, e6); n6 = pk_fma(e6, vv, n6);
            d7 = pk_add(d7, e7); n7 = pk_fma(e7, vv, n7);
        }
    }

    float* op = out + (size_t)(m0 + r) * H_DIM + sub * 16;
    f32x4 o0, o1, o2, o3;
    o0.x = n0.x / d0.x; o0.y = n0.y / d0.y; o0.z = n1.x / d1.x; o0.w = n1.y / d1.y;
    o1.x = n2.x / d2.x; o1.y = n2.y / d2.y; o1.z = n3.x / d3.x; o1.w = n3.y / d3.y;
    o2.x = n4.x / d4.x; o2.y = n4.y / d4.y; o2.z = n5.x / d5.x; o2.w = n5.y / d5.y;
    o3.x = n6.x / d6.x; o3.y = n6.y / d6.y; o3.z = n7.x / d7.x; o3.w = n7.y / d7.y;
    __builtin_nontemporal_store(o0, (f32x4*)(op +  0));
    __builtin_nontemporal_store(o1, (f32x4*)(op +  4));
    __builtin_nontemporal_store(o2, (f32x4*)(op +  8));
    __builtin_nontemporal_store(o3, (f32x4*)(op + 12));
}

// ---------------------------------------------------------------------------
extern "C" void kernel_launch(void* const* d_in, const int* in_sizes, int n_in,
                              void* d_out, int out_size, void* d_ws, size_t ws_size,
                              hipStream_t stream)
{
    const float* x  = (const float*)d_in[0];
    const float* wq = (const float*)d_in[1];
    const float* wk = (const float*)d_in[2];
    const float* wv = (const float*)d_in[3];
    float* out = (float*)d_out;

    u16* wt2 = (u16*)d_ws;   // 49*384*32 u16 = 1.2 MB

    wtrans_kernel<<<dim3(K_DIM / 32, H_DIM / 32, 3), 256, 0, stream>>>(wq, wk, wv, wt2);
    fused_kernel<<<M_ROWS / MT, 512, 0, stream>>>(x, wt2, out);
}